// Round 16
// baseline (362.778 us; speedup 1.0000x reference)
//
#include <hip/hip_runtime.h>
#include <hip/hip_bf16.h>
#include <cstddef>

#define B_   8
#define N_   1024
#define C_   768
#define NH_  12
#define HD_  64
#define M_   (B_ * N_)   // 8192

typedef __attribute__((ext_vector_type(8))) short  short8;
typedef __attribute__((ext_vector_type(4))) float  f32x4;

__device__ __forceinline__ unsigned short f2b(float f) {
    union { float f; unsigned u; } v; v.f = f;
    unsigned u = v.u;
    return (unsigned short)((u + 0x7FFFu + ((u >> 16) & 1u)) >> 16);
}
__device__ __forceinline__ float b2f(unsigned short s) {
    union { unsigned u; float f; } v; v.u = ((unsigned)s) << 16;
    return v.f;
}
// packed f32x2 -> bf16x2 (v_cvt_pk_bf16_f32), RTNE
__device__ __forceinline__ ushort2 pk2(float a, float b) {
    __hip_bfloat162 t = __float22bfloat162_rn(make_float2(a, b));
    return *(ushort2*)&t;
}
// async global->LDS, 16 B per lane; lds dest = base + lane*16 (wave-uniform base)
__device__ __forceinline__ void gld16(const unsigned short* g, unsigned short* l) {
    __builtin_amdgcn_global_load_lds(
        (const __attribute__((address_space(1))) void*)g,
        (__attribute__((address_space(3))) void*)l, 16, 0, 0);
}

// ---------------- fused pre-pass: transpose(2304 blocks) + cast/bias ------
__global__ __launch_bounds__(256) void prepass_kernel(
    const float* __restrict__ x,
    const float* __restrict__ w0, const float* __restrict__ w1,
    const float* __restrict__ w2, const float* __restrict__ w3,
    const float* __restrict__ ab, const float* __restrict__ hbias,
    unsigned short* __restrict__ xb,
    unsigned short* __restrict__ t0, unsigned short* __restrict__ t1,
    unsigned short* __restrict__ t2, unsigned short* __restrict__ t3,
    unsigned short* __restrict__ bc) {
    const int bid = blockIdx.x;
    if (bid < 2304) {
        const int z = bid / 576, t = bid % 576;
        const float* src = (z == 0) ? w0 : (z == 1) ? w1 : (z == 2) ? w2 : w3;
        unsigned short* dst = (z == 0) ? t0 : (z == 1) ? t1 : (z == 2) ? t2 : t3;
        __shared__ float tile[32][33];
        const int r0 = (t / 24) * 32, c0 = (t % 24) * 32;
        const int tx = threadIdx.x & 31, ty = threadIdx.x >> 5;
        #pragma unroll
        for (int p = 0; p < 4; ++p)
            tile[ty + 8 * p][tx] = src[(size_t)(r0 + ty + 8 * p) * C_ + c0 + tx];
        __syncthreads();
        #pragma unroll
        for (int p = 0; p < 4; ++p)
            dst[(size_t)(c0 + ty + 8 * p) * C_ + r0 + tx] = f2b(tile[tx][ty + 8 * p]);
    } else {
        const int castN4 = M_ * C_ / 4;
        const int biasN4 = NH_ * N_ * N_ / 4;
        const int qm4 = N_ * N_ / 4;
        const int stride = (4096 - 2304) * 256;
        for (int i = (bid - 2304) * 256 + threadIdx.x; i < castN4 + biasN4; i += stride) {
            if (i < castN4) {
                float4 v = ((const float4*)x)[i];
                ushort2 lo = pk2(v.x, v.y), hi = pk2(v.z, v.w);
                ushort4 o; o.x = lo.x; o.y = lo.y; o.z = hi.x; o.w = hi.y;
                ((ushort4*)xb)[i] = o;
            } else {
                int j = i - castN4;
                float4 a = ((const float4*)ab)[j % qm4];
                float4 h = ((const float4*)hbias)[j];
                ushort2 lo = pk2(a.x + h.x, a.y + h.y), hi = pk2(a.z + h.z, a.w + h.w);
                ushort4 o; o.x = lo.x; o.y = lo.y; o.z = hi.x; o.w = hi.y;
                ((ushort4*)bc)[j] = o;
            }
        }
    }
}

// ---------------- QKV GEMM: 128x128 tile, BK=32, global_load_lds ----------
__global__ __launch_bounds__(256) void qkv_gemm(
    const unsigned short* __restrict__ A,
    const unsigned short* __restrict__ W0, const unsigned short* __restrict__ W1,
    const unsigned short* __restrict__ W2,
    unsigned short* __restrict__ o0, unsigned short* __restrict__ o1,
    unsigned short* __restrict__ o2) {
    __shared__ unsigned short As[128 * 32];
    __shared__ unsigned short Bs[128 * 32];
    const int z = blockIdx.z;
    const unsigned short* Bt = (z == 0) ? W0 : (z == 1) ? W1 : W2;
    const int tid = threadIdx.x;
    const int wid = tid >> 6, lane = tid & 63;
    const int ln = lane & 15, g = lane >> 4;
    const int wm = wid >> 1, wn = wid & 1;
    const int bm = blockIdx.y * 128, bn = blockIdx.x * 128;
    const int lrow = lane >> 2, lch = (lane & 3) * 8;

    f32x4 acc[4][4];
    #pragma unroll
    for (int i = 0; i < 4; ++i)
        #pragma unroll
        for (int j = 0; j < 4; ++j) acc[i][j] = (f32x4)0.f;

    for (int k0 = 0; k0 < C_; k0 += 32) {
        #pragma unroll
        for (int p = 0; p < 2; ++p) {
            const int rowbase = (wid + p * 4) * 16;
            gld16(&A [(size_t)(bm + rowbase + lrow) * C_ + k0 + lch], &As[rowbase * 32]);
            gld16(&Bt[(size_t)(bn + rowbase + lrow) * C_ + k0 + lch], &Bs[rowbase * 32]);
        }
        __syncthreads();
        short8 a[4], b[4];
        #pragma unroll
        for (int mt = 0; mt < 4; ++mt)
            a[mt] = *(const short8*)&As[(wm * 64 + mt * 16 + ln) * 32 + g * 8];
        #pragma unroll
        for (int nt = 0; nt < 4; ++nt)
            b[nt] = *(const short8*)&Bs[(wn * 64 + nt * 16 + ln) * 32 + g * 8];
        #pragma unroll
        for (int mt = 0; mt < 4; ++mt)
            #pragma unroll
            for (int nt = 0; nt < 4; ++nt)
                acc[mt][nt] = __builtin_amdgcn_mfma_f32_16x16x32_bf16(
                    a[mt], b[nt], acc[mt][nt], 0, 0, 0);
        __syncthreads();
    }

    unsigned short* outp = (z == 0) ? o0 : (z == 1) ? o1 : o2;
    #pragma unroll
    for (int mt = 0; mt < 4; ++mt) {
        #pragma unroll
        for (int nt = 0; nt < 4; ++nt) {
            f32x4 c = acc[mt][nt];
            int rowb = bm + wm * 64 + mt * 16 + g * 4;
            int col  = bn + wn * 64 + nt * 16 + ln;
            int hh = col >> 6, dd = col & 63;
            if (z < 2) {
                #pragma unroll
                for (int i = 0; i < 4; ++i) {
                    int row = rowb + i;
                    int bb = row >> 10, n = row & 1023;
                    outp[((size_t)(bb * NH_ + hh) * N_ + n) * HD_ + dd] = f2b(c[i]);
                }
            } else {
                int bb = rowb >> 10, n0 = rowb & 1023;
                ushort2 lo = pk2(c[0], c[1]), hi = pk2(c[2], c[3]);
                ushort4 pk; pk.x = lo.x; pk.y = lo.y; pk.z = hi.x; pk.w = hi.y;
                *(ushort4*)&outp[((size_t)(bb * NH_ + hh) * HD_ + dd) * N_ + n0] = pk;
            }
        }
    }
}

// ---------------- proj GEMM: 128x128 tile, BK=32, global_load_lds ---------
__global__ __launch_bounds__(256) void proj_gemm(
    const unsigned short* __restrict__ A, const unsigned short* __restrict__ Bt,
    const float* __restrict__ bias, float* __restrict__ outp) {
    __shared__ unsigned short As[128 * 32];
    __shared__ unsigned short Bs[128 * 32];
    const int tid = threadIdx.x;
    const int wid = tid >> 6, lane = tid & 63;
    const int ln = lane & 15, g = lane >> 4;
    const int wm = wid >> 1, wn = wid & 1;
    const int bm = blockIdx.y * 128, bn = blockIdx.x * 128;
    const int lrow = lane >> 2, lch = (lane & 3) * 8;

    f32x4 acc[4][4];
    #pragma unroll
    for (int i = 0; i < 4; ++i)
        #pragma unroll
        for (int j = 0; j < 4; ++j) acc[i][j] = (f32x4)0.f;

    for (int k0 = 0; k0 < C_; k0 += 32) {
        #pragma unroll
        for (int p = 0; p < 2; ++p) {
            const int rowbase = (wid + p * 4) * 16;
            gld16(&A [(size_t)(bm + rowbase + lrow) * C_ + k0 + lch], &As[rowbase * 32]);
            gld16(&Bt[(size_t)(bn + rowbase + lrow) * C_ + k0 + lch], &Bs[rowbase * 32]);
        }
        __syncthreads();
        short8 a[4], b[4];
        #pragma unroll
        for (int mt = 0; mt < 4; ++mt)
            a[mt] = *(const short8*)&As[(wm * 64 + mt * 16 + ln) * 32 + g * 8];
        #pragma unroll
        for (int nt = 0; nt < 4; ++nt)
            b[nt] = *(const short8*)&Bs[(wn * 64 + nt * 16 + ln) * 32 + g * 8];
        #pragma unroll
        for (int mt = 0; mt < 4; ++mt)
            #pragma unroll
            for (int nt = 0; nt < 4; ++nt)
                acc[mt][nt] = __builtin_amdgcn_mfma_f32_16x16x32_bf16(
                    a[mt], b[nt], acc[mt][nt], 0, 0, 0);
        __syncthreads();
    }

    #pragma unroll
    for (int mt = 0; mt < 4; ++mt) {
        #pragma unroll
        for (int nt = 0; nt < 4; ++nt) {
            f32x4 c = acc[mt][nt];
            int rowb = bm + wm * 64 + mt * 16 + g * 4;
            int col  = bn + wn * 64 + nt * 16 + ln;
            float bb = bias[col];
            #pragma unroll
            for (int i = 0; i < 4; ++i)
                outp[(size_t)(rowb + i) * C_ + col] = c[i] + bb;
        }
    }
}

// ---------------- fused attention: batch-pipelined, double-buffered -------
// Grid 1536: id -> bp = id&1 (4-batch half), qbh = id>>1 -> (qb0, h).
// 16 q-rows/block, 512 thr = 8 waves. Per iteration i (b = bp*4+i):
//   [QK^T(b+1) -> buf^1]  ||  [softmax(b) + attn f32 stores]   (one interval)
//   mid barrier; PV(b) (kt-split waves + LDS reduce).
__global__ __launch_bounds__(512) void attn_fused(
    const unsigned short* __restrict__ qh, const unsigned short* __restrict__ kh,
    const unsigned short* __restrict__ vt,
    const unsigned short* __restrict__ bias_c,
    float* __restrict__ attn_out, unsigned short* __restrict__ hb) {
    __shared__ unsigned short sc[2][16 * 1024];   // 2 x 32 KB
    __shared__ f32x4 red[4][64];                  // 4 KB
    __shared__ float sinv[16];
    const int id = blockIdx.x;
    const int bp = id & 1;
    const int qbh = id >> 1;                      // 0..767
    const int qb0 = (qbh / NH_) * 16;
    const int h = qbh % NH_;
    const int tid = threadIdx.x;
    const int wid = tid >> 6, lane = tid & 63;
    const int ln = lane & 15, g = lane >> 4;

    #define SCP(bufi, row, m) ((unsigned short*)((char*)sc[bufi] + (row) * 2048 + \
                               (((m) * 2) ^ (((row) & 7) << 4))))

    auto qkt = [&](int b, int bufi) {
        const int bh = b * NH_ + h;
        short8 qf0 = *(const short8*)&qh[((size_t)bh * N_ + qb0 + ln) * HD_ + g * 8];
        short8 qf1 = *(const short8*)&qh[((size_t)bh * N_ + qb0 + ln) * HD_ + 32 + g * 8];
        const unsigned short* kbase = kh + (size_t)bh * N_ * HD_;
        const int mb = wid * 128;
        short8 k0 = *(const short8*)&kbase[(size_t)(mb + ln) * HD_ + g * 8];
        short8 k1 = *(const short8*)&kbase[(size_t)(mb + ln) * HD_ + 32 + g * 8];
        #pragma unroll
        for (int mt = 0; mt < 8; ++mt) {
            const int m0 = mb + mt * 16;
            const int m1 = (mt < 7) ? m0 + 16 : m0;     // clamped prefetch
            short8 n0 = *(const short8*)&kbase[(size_t)(m1 + ln) * HD_ + g * 8];
            short8 n1 = *(const short8*)&kbase[(size_t)(m1 + ln) * HD_ + 32 + g * 8];
            f32x4 s = (f32x4)0.f;
            s = __builtin_amdgcn_mfma_f32_16x16x32_bf16(k0, qf0, s, 0, 0, 0);
            s = __builtin_amdgcn_mfma_f32_16x16x32_bf16(k1, qf1, s, 0, 0, 0);
            const int mrow = m0 + g * 4;
            ushort2 lo = pk2(s[0] * 0.125f, s[1] * 0.125f);
            ushort2 hi = pk2(s[2] * 0.125f, s[3] * 0.125f);
            ushort4 pk; pk.x = lo.x; pk.y = lo.y; pk.z = hi.x; pk.w = hi.y;
            *(ushort4*)SCP(bufi, ln, mrow) = pk;
            k0 = n0; k1 = n1;
        }
    };

    qkt(bp * 4, 0);                               // prologue

    for (int i = 0; i < 4; ++i) {
        const int b = bp * 4 + i;
        const int bufi = i & 1;
        __syncthreads();                          // buf[bufi] ready; prev PV done

        // ---- section 1: QK^T(b+1) (independent) + softmax(b) + stores ----
        if (i < 3) qkt(b + 1, bufi ^ 1);

        const int r2 = tid >> 5, t32 = tid & 31;
        {
            const unsigned short* brow = bias_c + ((size_t)h * N_ + qb0 + r2) * N_;
            float sv[4][8];
            float mx = -1e30f;
            #pragma unroll
            for (int j = 0; j < 4; ++j) {
                const int m = t32 * 8 + j * 256;
                short8 er = *(const short8*)SCP(bufi, r2, m);
                short8 bb = *(const short8*)&brow[m];
                #pragma unroll
                for (int e = 0; e < 8; ++e) {
                    sv[j][e] = b2f((unsigned short)er[e]) + b2f((unsigned short)bb[e]);
                    mx = fmaxf(mx, sv[j][e]);
                }
            }
            #pragma unroll
            for (int off = 16; off; off >>= 1) mx = fmaxf(mx, __shfl_xor(mx, off, 32));
            float sum = 0.f;
            #pragma unroll
            for (int j = 0; j < 4; ++j) {
                #pragma unroll
                for (int e = 0; e < 8; ++e) {
                    sv[j][e] = __expf(sv[j][e] - mx);
                    sum += sv[j][e];
                }
                ushort2 p0 = pk2(sv[j][0], sv[j][1]);
                ushort2 p1 = pk2(sv[j][2], sv[j][3]);
                ushort2 p2 = pk2(sv[j][4], sv[j][5]);
                ushort2 p3 = pk2(sv[j][6], sv[j][7]);
                short8 pk;
                pk[0] = p0.x; pk[1] = p0.y; pk[2] = p1.x; pk[3] = p1.y;
                pk[4] = p2.x; pk[5] = p2.y; pk[6] = p3.x; pk[7] = p3.y;
                *(short8*)SCP(bufi, r2, t32 * 8 + j * 256) = pk;
            }
            #pragma unroll
            for (int off = 16; off; off >>= 1) sum += __shfl_xor(sum, off, 32);
            const float inv = 1.f / sum;
            if (t32 == 0) sinv[r2] = inv;
            float* arow = attn_out + (((size_t)(b * NH_ + h) * N_) + qb0 + r2) * N_ + t32 * 8;
            #pragma unroll
            for (int j = 0; j < 4; ++j) {
                f32x4 o0, o1;
                o0[0] = sv[j][0] * inv; o0[1] = sv[j][1] * inv;
                o0[2] = sv[j][2] * inv; o0[3] = sv[j][3] * inv;
                o1[0] = sv[j][4] * inv; o1[1] = sv[j][5] * inv;
                o1[2] = sv[j][6] * inv; o1[3] = sv[j][7] * inv;
                __builtin_nontemporal_store(o0, (f32x4*)&arow[j * 256]);
                __builtin_nontemporal_store(o1, (f32x4*)&arow[j * 256 + 4]);
            }
        }
        __syncthreads();                          // e in LDS + sinv ready

        // ---- section 2: PV(b), kt-split across wave halves ---------------
        {
            const int nt = wid & 3, khf = wid >> 2;
            const unsigned short* vrow =
                vt + ((size_t)(b * NH_ + h) * HD_ + nt * 16 + ln) * N_;
            f32x4 acc = (f32x4)0.f;
            const int kb0 = khf * 16;
            short8 pa = *(const short8*)SCP(bufi, ln, kb0 * 32 + g * 8);
            short8 vb = *(const short8*)&vrow[kb0 * 32 + g * 8];
            #pragma unroll
            for (int kt = 0; kt < 16; ++kt) {
                const int kn = kb0 + ((kt < 15) ? kt + 1 : kt);
                short8 npa = *(const short8*)SCP(bufi, ln, kn * 32 + g * 8);
                short8 nvb = *(const short8*)&vrow[kn * 32 + g * 8];
                acc = __builtin_amdgcn_mfma_f32_16x16x32_bf16(pa, vb, acc, 0, 0, 0);
                pa = npa; vb = nvb;
            }
            if (khf == 1) red[nt][lane] = acc;
            __syncthreads();
            if (khf == 0) {
                acc += red[nt][lane];
                const int col = h * HD_ + nt * 16 + ln;
                #pragma unroll
                for (int i2 = 0; i2 < 4; ++i2) {
                    int q = qb0 + g * 4 + i2;
                    hb[(size_t)((b << 10) + q) * C_ + col] =
                        f2b(acc[i2] * sinv[g * 4 + i2]);
                }
            }
        }
    }
    #undef SCP
}

extern "C" void kernel_launch(void* const* d_in, const int* in_sizes, int n_in,
                              void* d_out, int out_size, void* d_ws, size_t ws_size,
                              hipStream_t stream) {
    const float* x         = (const float*)d_in[0];
    const float* Wq        = (const float*)d_in[1];
    const float* Wk        = (const float*)d_in[2];
    const float* Wv        = (const float*)d_in[3];
    const float* Wproj     = (const float*)d_in[4];
    const float* proj_b    = (const float*)d_in[5];
    const float* attn_bias = (const float*)d_in[6];
    const float* head_bias = (const float*)d_in[7];

    float* out  = (float*)d_out;                       // [B,N,C]
    float* attn = out + (size_t)B_ * N_ * C_;          // [B,NH,N,N]

    unsigned short* ws = (unsigned short*)d_ws;
    const size_t SZ_X = (size_t)M_ * C_;               // 6291456
    const size_t SZ_W = (size_t)C_ * C_;               // 589824
    unsigned short* xb  = ws;
    unsigned short* wqt = xb + SZ_X;
    unsigned short* wkt = wqt + SZ_W;
    unsigned short* wvt = wkt + SZ_W;
    unsigned short* wpt = wvt + SZ_W;
    unsigned short* qh  = wpt + SZ_W;     // [B,NH,N,64] bf16
    unsigned short* khd = qh + SZ_X;      // [B,NH,N,64] bf16
    unsigned short* vtp = khd + SZ_X;     // [B,NH,64,N] bf16
    unsigned short* bc  = vtp + SZ_X;     // [NH,N,N] bf16, 25.2 MB
    unsigned short* hb  = xb;             // alias: xb dead after QKV GEMMs

    prepass_kernel<<<4096, 256, 0, stream>>>(
        x, Wq, Wk, Wv, Wproj, attn_bias, head_bias,
        xb, wqt, wkt, wvt, wpt, bc);

    qkv_gemm<<<dim3(C_ / 128, M_ / 128, 3), 256, 0, stream>>>(
        xb, wqt, wkt, wvt, qh, khd, vtp);

    attn_fused<<<dim3(1536), 512, 0, stream>>>(
        qh, khd, vtp, bc, attn, hb);

    proj_gemm<<<dim3(C_ / 128, M_ / 128), 256, 0, stream>>>(hb, wpt, proj_b, out);
}

// Round 17
// 292.822 us; speedup vs baseline: 1.2389x; 1.2389x over previous
//
#include <hip/hip_runtime.h>
#include <hip/hip_bf16.h>
#include <cstddef>

#define B_   8
#define N_   1024
#define C_   768
#define NH_  12
#define HD_  64
#define M_   (B_ * N_)   // 8192

typedef __attribute__((ext_vector_type(8))) short  short8;
typedef __attribute__((ext_vector_type(4))) float  f32x4;

__device__ __forceinline__ unsigned short f2b(float f) {
    union { float f; unsigned u; } v; v.f = f;
    unsigned u = v.u;
    return (unsigned short)((u + 0x7FFFu + ((u >> 16) & 1u)) >> 16);
}
__device__ __forceinline__ float b2f(unsigned short s) {
    union { unsigned u; float f; } v; v.u = ((unsigned)s) << 16;
    return v.f;
}
// packed f32x2 -> bf16x2 (v_cvt_pk_bf16_f32), RTNE
__device__ __forceinline__ ushort2 pk2(float a, float b) {
    __hip_bfloat162 t = __float22bfloat162_rn(make_float2(a, b));
    return *(ushort2*)&t;
}
// async global->LDS, 16 B per lane; lds dest = base + lane*16 (wave-uniform base)
__device__ __forceinline__ void gld16(const unsigned short* g, unsigned short* l) {
    __builtin_amdgcn_global_load_lds(
        (const __attribute__((address_space(1))) void*)g,
        (__attribute__((address_space(3))) void*)l, 16, 0, 0);
}

// ---------------- fused pre-pass: transpose(2304 blocks) + cast/bias ------
__global__ __launch_bounds__(256) void prepass_kernel(
    const float* __restrict__ x,
    const float* __restrict__ w0, const float* __restrict__ w1,
    const float* __restrict__ w2, const float* __restrict__ w3,
    const float* __restrict__ ab, const float* __restrict__ hbias,
    unsigned short* __restrict__ xb,
    unsigned short* __restrict__ t0, unsigned short* __restrict__ t1,
    unsigned short* __restrict__ t2, unsigned short* __restrict__ t3,
    unsigned short* __restrict__ bc) {
    const int bid = blockIdx.x;
    if (bid < 2304) {
        const int z = bid / 576, t = bid % 576;
        const float* src = (z == 0) ? w0 : (z == 1) ? w1 : (z == 2) ? w2 : w3;
        unsigned short* dst = (z == 0) ? t0 : (z == 1) ? t1 : (z == 2) ? t2 : t3;
        __shared__ float tile[32][33];
        const int r0 = (t / 24) * 32, c0 = (t % 24) * 32;
        const int tx = threadIdx.x & 31, ty = threadIdx.x >> 5;
        #pragma unroll
        for (int p = 0; p < 4; ++p)
            tile[ty + 8 * p][tx] = src[(size_t)(r0 + ty + 8 * p) * C_ + c0 + tx];
        __syncthreads();
        #pragma unroll
        for (int p = 0; p < 4; ++p)
            dst[(size_t)(c0 + ty + 8 * p) * C_ + r0 + tx] = f2b(tile[tx][ty + 8 * p]);
    } else {
        const int castN4 = M_ * C_ / 4;                  // 1572864
        const int biasN4 = NH_ * N_ * N_ / 4;            // 3145728
        const int qm4 = N_ * N_ / 4;
        const int stride = (4096 - 2304) * 256;
        for (int i = (bid - 2304) * 256 + threadIdx.x; i < castN4 + biasN4; i += stride) {
            if (i < castN4) {
                float4 v = ((const float4*)x)[i];
                ushort2 lo = pk2(v.x, v.y), hi = pk2(v.z, v.w);
                ushort4 o; o.x = lo.x; o.y = lo.y; o.z = hi.x; o.w = hi.y;
                ((ushort4*)xb)[i] = o;
            } else {
                int j = i - castN4;
                float4 a = ((const float4*)ab)[j % qm4];
                float4 h = ((const float4*)hbias)[j];
                ushort2 lo = pk2(a.x + h.x, a.y + h.y), hi = pk2(a.z + h.z, a.w + h.w);
                ushort4 o; o.x = lo.x; o.y = lo.y; o.z = hi.x; o.w = hi.y;
                ((ushort4*)bc)[j] = o;
            }
        }
    }
}

// ---------------- QKV GEMM: 128x128 tile, BK=32, global_load_lds ----------
__global__ __launch_bounds__(256) void qkv_gemm(
    const unsigned short* __restrict__ A,
    const unsigned short* __restrict__ W0, const unsigned short* __restrict__ W1,
    const unsigned short* __restrict__ W2,
    unsigned short* __restrict__ o0, unsigned short* __restrict__ o1,
    unsigned short* __restrict__ o2) {
    __shared__ unsigned short As[128 * 32];   // linear [row][k], 64 B rows
    __shared__ unsigned short Bs[128 * 32];
    const int z = blockIdx.z;
    const unsigned short* Bt = (z == 0) ? W0 : (z == 1) ? W1 : W2;
    const int tid = threadIdx.x;
    const int wid = tid >> 6, lane = tid & 63;
    const int ln = lane & 15, g = lane >> 4;
    const int wm = wid >> 1, wn = wid & 1;
    const int bm = blockIdx.y * 128, bn = blockIdx.x * 128;
    const int lrow = lane >> 2, lch = (lane & 3) * 8;

    f32x4 acc[4][4];
    #pragma unroll
    for (int i = 0; i < 4; ++i)
        #pragma unroll
        for (int j = 0; j < 4; ++j) acc[i][j] = (f32x4)0.f;

    for (int k0 = 0; k0 < C_; k0 += 32) {
        #pragma unroll
        for (int p = 0; p < 2; ++p) {
            const int rowbase = (wid + p * 4) * 16;     // wave-uniform
            gld16(&A [(size_t)(bm + rowbase + lrow) * C_ + k0 + lch], &As[rowbase * 32]);
            gld16(&Bt[(size_t)(bn + rowbase + lrow) * C_ + k0 + lch], &Bs[rowbase * 32]);
        }
        __syncthreads();
        short8 a[4], b[4];
        #pragma unroll
        for (int mt = 0; mt < 4; ++mt)
            a[mt] = *(const short8*)&As[(wm * 64 + mt * 16 + ln) * 32 + g * 8];
        #pragma unroll
        for (int nt = 0; nt < 4; ++nt)
            b[nt] = *(const short8*)&Bs[(wn * 64 + nt * 16 + ln) * 32 + g * 8];
        #pragma unroll
        for (int mt = 0; mt < 4; ++mt)
            #pragma unroll
            for (int nt = 0; nt < 4; ++nt)
                acc[mt][nt] = __builtin_amdgcn_mfma_f32_16x16x32_bf16(
                    a[mt], b[nt], acc[mt][nt], 0, 0, 0);
        __syncthreads();
    }

    unsigned short* outp = (z == 0) ? o0 : (z == 1) ? o1 : o2;
    #pragma unroll
    for (int mt = 0; mt < 4; ++mt) {
        #pragma unroll
        for (int nt = 0; nt < 4; ++nt) {
            f32x4 c = acc[mt][nt];
            int rowb = bm + wm * 64 + mt * 16 + g * 4;
            int col  = bn + wn * 64 + nt * 16 + ln;
            int hh = col >> 6, dd = col & 63;
            if (z < 2) {
                #pragma unroll
                for (int i = 0; i < 4; ++i) {
                    int row = rowb + i;
                    int bb = row >> 10, n = row & 1023;
                    outp[((size_t)(bb * NH_ + hh) * N_ + n) * HD_ + dd] = f2b(c[i]);
                }
            } else {
                int bb = rowb >> 10, n0 = rowb & 1023;
                ushort2 lo = pk2(c[0], c[1]), hi = pk2(c[2], c[3]);
                ushort4 pk; pk.x = lo.x; pk.y = lo.y; pk.z = hi.x; pk.w = hi.y;
                *(ushort4*)&outp[((size_t)(bb * NH_ + hh) * HD_ + dd) * N_ + n0] = pk;
            }
        }
    }
}

// ---------------- proj GEMM: 128x128 tile, BK=32, global_load_lds ---------
__global__ __launch_bounds__(256) void proj_gemm(
    const unsigned short* __restrict__ A, const unsigned short* __restrict__ Bt,
    const float* __restrict__ bias, float* __restrict__ outp) {
    __shared__ unsigned short As[128 * 32];
    __shared__ unsigned short Bs[128 * 32];
    const int tid = threadIdx.x;
    const int wid = tid >> 6, lane = tid & 63;
    const int ln = lane & 15, g = lane >> 4;
    const int wm = wid >> 1, wn = wid & 1;
    const int bm = blockIdx.y * 128, bn = blockIdx.x * 128;
    const int lrow = lane >> 2, lch = (lane & 3) * 8;

    f32x4 acc[4][4];
    #pragma unroll
    for (int i = 0; i < 4; ++i)
        #pragma unroll
        for (int j = 0; j < 4; ++j) acc[i][j] = (f32x4)0.f;

    for (int k0 = 0; k0 < C_; k0 += 32) {
        #pragma unroll
        for (int p = 0; p < 2; ++p) {
            const int rowbase = (wid + p * 4) * 16;
            gld16(&A [(size_t)(bm + rowbase + lrow) * C_ + k0 + lch], &As[rowbase * 32]);
            gld16(&Bt[(size_t)(bn + rowbase + lrow) * C_ + k0 + lch], &Bs[rowbase * 32]);
        }
        __syncthreads();
        short8 a[4], b[4];
        #pragma unroll
        for (int mt = 0; mt < 4; ++mt)
            a[mt] = *(const short8*)&As[(wm * 64 + mt * 16 + ln) * 32 + g * 8];
        #pragma unroll
        for (int nt = 0; nt < 4; ++nt)
            b[nt] = *(const short8*)&Bs[(wn * 64 + nt * 16 + ln) * 32 + g * 8];
        #pragma unroll
        for (int mt = 0; mt < 4; ++mt)
            #pragma unroll
            for (int nt = 0; nt < 4; ++nt)
                acc[mt][nt] = __builtin_amdgcn_mfma_f32_16x16x32_bf16(
                    a[mt], b[nt], acc[mt][nt], 0, 0, 0);
        __syncthreads();
    }

    #pragma unroll
    for (int mt = 0; mt < 4; ++mt) {
        #pragma unroll
        for (int nt = 0; nt < 4; ++nt) {
            f32x4 c = acc[mt][nt];
            int rowb = bm + wm * 64 + mt * 16 + g * 4;
            int col  = bn + wn * 64 + nt * 16 + ln;
            float bb = bias[col];
            #pragma unroll
            for (int i = 0; i < 4; ++i)
                outp[(size_t)(rowb + i) * C_ + col] = c[i] + bb;
        }
    }
}

// ---------------- fused attention (best: store-interleaved PV) ------------
__global__ __launch_bounds__(512, 4) void attn_fused(
    const unsigned short* __restrict__ qh, const unsigned short* __restrict__ kh,
    const unsigned short* __restrict__ vt,
    const unsigned short* __restrict__ bias_c,
    float* __restrict__ attn_out, unsigned short* __restrict__ hb) {
    __shared__ unsigned short sc[32 * 1024];
    __shared__ float sinv[32];
    const int id = blockIdx.x;
    const int xcd = id & 7;
    const int b = (id >> 3) & 7;
    const int qbh = ((id >> 6) << 3) + xcd;     // 0..383
    const int qb0 = (qbh / NH_) * 32;
    const int h = qbh % NH_;
    const int bh = b * NH_ + h;
    const int tid = threadIdx.x;
    const int wid = tid >> 6, lane = tid & 63;
    const int ln = lane & 15, g = lane >> 4;

    #define SCP(row, m) ((unsigned short*)((char*)sc + (row) * 2048 + \
                         (((m) * 2) ^ (((row) & 7) << 4))))

    // ---- phase 1: swapped QK^T + scale -> LDS (bf16), no bias ------------
    {
        short8 qf[2][2];
        #pragma unroll
        for (int Mt = 0; Mt < 2; ++Mt)
            #pragma unroll
            for (int kc = 0; kc < 2; ++kc)
                qf[Mt][kc] = *(const short8*)&qh[
                    ((size_t)bh * N_ + qb0 + Mt * 16 + ln) * HD_ + kc * 32 + g * 8];
        const int mb = wid * 128;
        const unsigned short* kbase = kh + (size_t)bh * N_ * HD_;
        short8 k0 = *(const short8*)&kbase[(size_t)(mb + ln) * HD_ + g * 8];
        short8 k1 = *(const short8*)&kbase[(size_t)(mb + ln) * HD_ + 32 + g * 8];
        for (int mt = 0; mt < 8; ++mt) {
            const int m0 = mb + mt * 16;
            const int m1 = (mt < 7) ? m0 + 16 : m0;     // clamped prefetch
            short8 n0 = *(const short8*)&kbase[(size_t)(m1 + ln) * HD_ + g * 8];
            short8 n1 = *(const short8*)&kbase[(size_t)(m1 + ln) * HD_ + 32 + g * 8];
            #pragma unroll
            for (int Mt = 0; Mt < 2; ++Mt) {
                f32x4 s = (f32x4)0.f;
                s = __builtin_amdgcn_mfma_f32_16x16x32_bf16(k0, qf[Mt][0], s, 0, 0, 0);
                s = __builtin_amdgcn_mfma_f32_16x16x32_bf16(k1, qf[Mt][1], s, 0, 0, 0);
                const int mrow = m0 + g * 4;
                ushort2 lo = pk2(s[0] * 0.125f, s[1] * 0.125f);
                ushort2 hi = pk2(s[2] * 0.125f, s[3] * 0.125f);
                ushort4 pk; pk.x = lo.x; pk.y = lo.y; pk.z = hi.x; pk.w = hi.y;
                *(ushort4*)SCP(Mt * 16 + ln, mrow) = pk;
            }
            k0 = n0; k1 = n1;
        }
    }
    __syncthreads();

    // ---- phase 2: softmax; e kept in sv[] regs AND written to LDS --------
    f32x4 sv[16];                     // e values, survive into phase 3
    const int r2 = tid >> 4, t16 = tid & 15;
    {
        const unsigned short* brow = bias_c + ((size_t)h * N_ + qb0 + r2) * N_;
        float mx = -1e30f;
        #pragma unroll
        for (int j = 0; j < 16; ++j) {
            ushort4 er = *(const ushort4*)SCP(r2, t16 * 4 + j * 64);
            ushort4 bb = *(const ushort4*)&brow[t16 * 4 + j * 64];
            sv[j][0] = b2f(er.x) + b2f(bb.x);
            sv[j][1] = b2f(er.y) + b2f(bb.y);
            sv[j][2] = b2f(er.z) + b2f(bb.z);
            sv[j][3] = b2f(er.w) + b2f(bb.w);
            mx = fmaxf(fmaxf(fmaxf(mx, sv[j][0]), fmaxf(sv[j][1], sv[j][2])), sv[j][3]);
        }
        #pragma unroll
        for (int off = 8; off; off >>= 1) mx = fmaxf(mx, __shfl_xor(mx, off, 16));
        float sum = 0.f;
        #pragma unroll
        for (int j = 0; j < 16; ++j) {
            float e0 = __expf(sv[j][0] - mx);
            float e1 = __expf(sv[j][1] - mx);
            float e2 = __expf(sv[j][2] - mx);
            float e3 = __expf(sv[j][3] - mx);
            sv[j][0] = e0; sv[j][1] = e1; sv[j][2] = e2; sv[j][3] = e3;
            sum += (e0 + e1) + (e2 + e3);
            ushort2 lo = pk2(e0, e1), hi = pk2(e2, e3);
            ushort4 pk; pk.x = lo.x; pk.y = lo.y; pk.z = hi.x; pk.w = hi.y;
            *(ushort4*)SCP(r2, t16 * 4 + j * 64) = pk;
        }
        #pragma unroll
        for (int off = 8; off; off >>= 1) sum += __shfl_xor(sum, off, 16);
        if (t16 == 0) sinv[r2] = 1.f / sum;
    }
    __syncthreads();

    // ---- phase 3: PV with attn stores interleaved into the MFMA loop -----
    {
        const float invr = sinv[r2];
        float* arow = attn_out + ((size_t)bh * N_ + qb0 + r2) * N_ + t16 * 4;
        const int Mt = wid >> 2, nt = wid & 3;
        const unsigned short* vrow = vt + ((size_t)bh * HD_ + nt * 16 + ln) * N_;
        f32x4 acc = (f32x4)0.f;
        short8 pa = *(const short8*)SCP(Mt * 16 + ln, g * 8);
        short8 vb = *(const short8*)&vrow[g * 8];
        #pragma unroll
        for (int kt2 = 0; kt2 < 16; ++kt2) {
            {   // kt = 2*kt2 ; prefetch kt+1
                const int kn = 2 * kt2 + 1;
                short8 npa = *(const short8*)SCP(Mt * 16 + ln, kn * 32 + g * 8);
                short8 nvb = *(const short8*)&vrow[kn * 32 + g * 8];
                acc = __builtin_amdgcn_mfma_f32_16x16x32_bf16(pa, vb, acc, 0, 0, 0);
                pa = npa; vb = nvb;
            }
            {   // interleaved attn store j = kt2 (independent of MFMA chain)
                f32x4 o;
                o[0] = sv[kt2][0] * invr; o[1] = sv[kt2][1] * invr;
                o[2] = sv[kt2][2] * invr; o[3] = sv[kt2][3] * invr;
                __builtin_nontemporal_store(o, (f32x4*)&arow[kt2 * 64]);
            }
            {   // kt = 2*kt2+1 ; prefetch kt+1 (clamped at end)
                const int kn = (kt2 < 15) ? 2 * kt2 + 2 : 2 * kt2 + 1;
                short8 npa = *(const short8*)SCP(Mt * 16 + ln, kn * 32 + g * 8);
                short8 nvb = *(const short8*)&vrow[kn * 32 + g * 8];
                acc = __builtin_amdgcn_mfma_f32_16x16x32_bf16(pa, vb, acc, 0, 0, 0);
                pa = npa; vb = nvb;
            }
        }
        #pragma unroll
        for (int i = 0; i < 4; ++i) {
            int q = qb0 + Mt * 16 + g * 4 + i;
            float o = acc[i] * sinv[Mt * 16 + g * 4 + i];
            hb[(size_t)((b << 10) + q) * C_ + h * HD_ + nt * 16 + ln] = f2b(o);
        }
    }
    #undef SCP
}

extern "C" void kernel_launch(void* const* d_in, const int* in_sizes, int n_in,
                              void* d_out, int out_size, void* d_ws, size_t ws_size,
                              hipStream_t stream) {
    const float* x         = (const float*)d_in[0];
    const float* Wq        = (const float*)d_in[1];
    const float* Wk        = (const float*)d_in[2];
    const float* Wv        = (const float*)d_in[3];
    const float* Wproj     = (const float*)d_in[4];
    const float* proj_b    = (const float*)d_in[5];
    const float* attn_bias = (const float*)d_in[6];
    const float* head_bias = (const float*)d_in[7];

    float* out  = (float*)d_out;                       // [B,N,C]
    float* attn = out + (size_t)B_ * N_ * C_;          // [B,NH,N,N]

    unsigned short* ws = (unsigned short*)d_ws;
    const size_t SZ_X = (size_t)M_ * C_;               // 6291456
    const size_t SZ_W = (size_t)C_ * C_;               // 589824
    unsigned short* xb  = ws;
    unsigned short* wqt = xb + SZ_X;
    unsigned short* wkt = wqt + SZ_W;
    unsigned short* wvt = wkt + SZ_W;
    unsigned short* wpt = wvt + SZ_W;
    unsigned short* qh  = wpt + SZ_W;     // [B,NH,N,64] bf16
    unsigned short* khd = qh + SZ_X;      // [B,NH,N,64] bf16
    unsigned short* vtp = khd + SZ_X;     // [B,NH,64,N] bf16
    unsigned short* bc  = vtp + SZ_X;     // [NH,N,N] bf16, 25.2 MB
    unsigned short* hb  = xb;             // alias: xb dead after QKV GEMMs

    prepass_kernel<<<4096, 256, 0, stream>>>(
        x, Wq, Wk, Wv, Wproj, attn_bias, head_bias,
        xb, wqt, wkt, wvt, wpt, bc);

    qkv_gemm<<<dim3(C_ / 128, M_ / 128, 3), 256, 0, stream>>>(
        xb, wqt, wkt, wvt, qh, khd, vtp);

    attn_fused<<<dim3(B_ * (N_ / 32) * NH_), 512, 0, stream>>>(
        qh, khd, vtp, bc, attn, hb);

    proj_gemm<<<dim3(C_ / 128, M_ / 128), 256, 0, stream>>>(hb, wpt, proj_b, out);
}